// Round 10
// baseline (733.122 us; speedup 1.0000x reference)
//
#include <hip/hip_runtime.h>
#include <hip/hip_fp16.h>

#define NN 50000
#define NE 800000
#define D 128
#define NH 4
#define NB 391   // (NN+127)/128 buckets of 128 nodes

typedef __attribute__((ext_vector_type(8))) short bf16x8;
typedef __attribute__((ext_vector_type(4))) float f32x4;

__device__ __forceinline__ float lrelu(float x){ return x > 0.f ? x : 0.2f*x; }
__device__ __forceinline__ float sel4(int h, float4 v){
  float r = v.x;
  r = (h==1)? v.y : r;
  r = (h==2)? v.z : r;
  r = (h==3)? v.w : r;
  return r;
}
__device__ __forceinline__ ushort f2bf(float f){
  union{ float f; uint i;} v; v.f=f;
  uint r = v.i + 0x7FFFu + ((v.i>>16)&1u);
  return (ushort)(r>>16);
}
__device__ __forceinline__ uint pack2bf(float x, float y){
  return (uint)f2bf(x) | ((uint)f2bf(y)<<16);
}
__device__ __forceinline__ float bflo(uint u){ return __uint_as_float(u<<16); }
__device__ __forceinline__ float bfhi(uint u){ return __uint_as_float(u & 0xffff0000u); }
__device__ __forceinline__ uint encf(float f){
  uint b = __float_as_uint(f);
  return (b & 0x80000000u) ? ~b : (b | 0x80000000u);
}
__device__ __forceinline__ float decf(uint e){
  return (e & 0x80000000u) ? __uint_as_float(e ^ 0x80000000u) : __uint_as_float(~e);
}
__device__ __forceinline__ uint f2h(float f){ return (uint)__half_as_ushort(__float2half(f)); }
__device__ __forceinline__ float h2f(uint u){ return __half2float(__ushort_as_half((ushort)u)); }

// ---------- CSR build: bucket histogram -> scan -> binned scatter -> bucket finalize ----------

__global__ void k_bhist(const int* __restrict__ dst, int* __restrict__ bcnt){
  __shared__ int c[NB];
  int t = threadIdx.x;
  for (int i=t;i<NB;i+=256) c[i]=0;
  __syncthreads();
  int base = blockIdx.x*4096;
  #pragma unroll
  for (int k=0;k<16;k++){
    int i = base + k*256 + t;
    if (i<NE) atomicAdd(&c[dst[i]>>7], 1);
  }
  __syncthreads();
  for (int i=t;i<NB;i+=256){ int v=c[i]; if (v) atomicAdd(&bcnt[i], v); }
}

__global__ void k_bscan(const int* __restrict__ bcnt, int* __restrict__ boff, int* __restrict__ bcur){
  __shared__ int sd[512];
  int t = threadIdx.x;
  int own = (t<NB)? bcnt[t] : 0;
  sd[t] = own;
  __syncthreads();
  for (int off=1; off<512; off<<=1){
    int v = (t>=off)? sd[t-off] : 0;
    __syncthreads();
    sd[t] += v;
    __syncthreads();
  }
  if (t<NB){
    int excl = sd[t]-own;
    boff[t]=excl; bcur[t]=excl;
  }
  if (t==0) boff[NB]=NE;
}

__global__ void k_binscat(const int* __restrict__ src, const int* __restrict__ dst,
                          const float* __restrict__ w, int* __restrict__ bcur,
                          uint2* __restrict__ stg){
  __shared__ int cnt[NB];
  __shared__ int st[NB];
  int t = threadIdx.x;
  for (int i=t;i<NB;i+=256) cnt[i]=0;
  __syncthreads();
  int base = blockIdx.x*4096;
  #pragma unroll
  for (int k=0;k<16;k++){
    int i = base + k*256 + t;
    if (i<NE) atomicAdd(&cnt[dst[i]>>7], 1);
  }
  __syncthreads();
  for (int i=t;i<NB;i+=256){
    int c = cnt[i];
    st[i] = c ? atomicAdd(&bcur[i], c) : 0;
    cnt[i] = 0;
  }
  __syncthreads();
  #pragma unroll
  for (int k=0;k<16;k++){
    int i = base + k*256 + t;
    if (i<NE){
      int d = dst[i];
      int b = d>>7;
      int pos = st[b] + atomicAdd(&cnt[b], 1);
      stg[pos] = make_uint2((uint)src[i] | ((uint)d<<16), __float_as_uint(w[i]));
    }
  }
}

// one block per bucket: exact CSR positions; writes offs + wpack (src | fp16(w)<<16)
__global__ void k_bfinal(const uint2* __restrict__ stg, const int* __restrict__ boff,
                         int* __restrict__ offs, uint* __restrict__ wpack){
  int b = blockIdx.x, t = threadIdx.x;
  int beg = boff[b], end = boff[b+1];
  int node0 = b<<7;
  int nnode = NN - node0; if (nnode>128) nnode=128;
  __shared__ int cnt[128];
  __shared__ int cur[128];
  if (t<128) cnt[t]=0;
  __syncthreads();
  for (int j=beg+t; j<end; j+=256)
    atomicAdd(&cnt[(stg[j].x>>16)&127], 1);
  __syncthreads();
  int own = (t<128)? cnt[t] : 0;
  for (int off=1; off<128; off<<=1){
    int v = (t<128 && t>=off)? cnt[t-off] : 0;
    __syncthreads();
    if (t<128) cnt[t] += v;
    __syncthreads();
  }
  if (t<128){
    int excl = cnt[t]-own;
    cur[t] = beg + excl;
    if (t<nnode) offs[node0+t] = beg + excl;
  }
  if (b==NB-1 && t==0) offs[NN]=NE;
  __syncthreads();
  for (int j=beg+t; j<end; j+=256){
    uint2 v = stg[j];
    int pos = atomicAdd(&cur[(v.x>>16)&127], 1);
    wpack[pos] = (v.x & 0xffffu) | (f2h(__uint_as_float(v.y))<<16);
  }
}

// ---------- conversions / prep ----------

// f32 [N,128] -> bf16-packed, column-sliced (slice = bid&7 for XCD-L2 affinity)
__global__ void k_cvt_slice(const float* __restrict__ in, uint* __restrict__ out16){
  int slice = blockIdx.x & 7;
  int id = (blockIdx.x>>3)*256 + threadIdx.x;
  if (id >= NN*8) return;
  int v = id>>3, cp = id&7;
  float2 f = *(const float2*)&in[(size_t)v*D + slice*16 + cp*2];
  out16[(size_t)v*64 + slice*8 + cp] = pack2bf(f.x, f.y);
}

// W f32 [k=128][n=128] -> Wtaug rows 0..127: bf16 packed [n][k/2 uints]
__global__ void k_cvtW(const float* __restrict__ W, uint* __restrict__ Wt){
  int i = blockIdx.x*256 + threadIdx.x;
  if (i < 128*64){
    int n = i>>6, k2 = i&63;
    float a = W[(size_t)(2*k2)*128 + n];
    float b = W[(size_t)(2*k2+1)*128 + n];
    Wt[i] = pack2bf(a,b);
  }
}

// rows 128..135 of Wtaug: Wal[k][h] = sum_i W[k][h*32+i]*a[h*32+i]
__global__ void k_prep(const float* __restrict__ W0, const float* __restrict__ al0,
                       const float* __restrict__ ar0, const float* __restrict__ W1,
                       const float* __restrict__ al1, const float* __restrict__ ar1,
                       uint* __restrict__ aug0, uint* __restrict__ aug1){
  __shared__ float sv[128][4];
  int b = blockIdx.x, t = threadIdx.x;   // 512 threads
  const float* W = (b<2)? W0 : W1;
  const float* a = (b==0)? al0 : (b==1)? ar0 : (b==2)? al1 : ar1;
  uint* o = (b<2)? aug0 : aug1;
  int rbase = (b&1)? 132 : 128;
  int d = t>>2, h = t&3;
  float s = 0.f;
  #pragma unroll
  for (int i=0;i<32;i++) s += W[d*128 + h*32 + i] * a[h*32 + i];
  sv[d][h] = s;
  __syncthreads();
  if (t<256){
    int h2 = t>>6, k2 = t&63;
    o[(rbase+h2)*64 + k2] = pack2bf(sv[2*k2][h2], sv[2*k2+1][h2]);
  }
}

// ---------- weighted aggregation, column-sliced: x[v] = h[v] + sum w_e h[src_e] ----------
// slice = bid&7 (XCD affinity); wave per node; lane = eg(8 edges)*8 + cp(8 col-pairs)
__global__ void k_wagg_slice(const float* __restrict__ hinF, const uint* __restrict__ hin16,
                             const int* __restrict__ offs, const uint* __restrict__ wpack,
                             uint* __restrict__ x16){
  int slice = blockIdx.x & 7;
  int node = ((blockIdx.x>>3)<<2) + (threadIdx.x>>6);
  int lane = threadIdx.x & 63;
  if (node>=NN) return;
  int eg = lane>>3, cp = lane&7;
  int beg=offs[node], end=offs[node+1];
  uint co = (uint)slice*32 + cp*4;   // byte offset within 256B row
  const char* hb = (const char*)hin16;
  float a0=0.f, a1=0.f;
  if (eg==0){
    if (hinF){
      float2 s2 = *(const float2*)&hinF[(size_t)node*D + slice*16 + cp*2];
      a0=s2.x; a1=s2.y;
    } else {
      uint su = hin16[(size_t)node*64 + slice*8 + cp];
      a0=bflo(su); a1=bfhi(su);
    }
  }
  for (int cb=beg; cb<end; cb+=8){
    int j = cb + eg;
    uint wp = wpack[j<end ? j : end-1];
    float w = (j<end)? h2f(wp>>16) : 0.f;
    uint u = *(const uint*)(hb + ((wp & 0xffffu)*256u + co));
    a0 = fmaf(bflo(u), w, a0);
    a1 = fmaf(bfhi(u), w, a1);
  }
  a0 += __shfl_xor(a0,8);  a1 += __shfl_xor(a1,8);
  a0 += __shfl_xor(a0,16); a1 += __shfl_xor(a1,16);
  a0 += __shfl_xor(a0,32); a1 += __shfl_xor(a1,32);
  if (eg==0)
    x16[(size_t)node*64 + slice*8 + cp] = pack2bf(a0,a1);
}

// ---------- MFMA GEMM (bf16 in, f32 acc), aug columns give el/er; shuffle-free epilogue ----------
__global__ __launch_bounds__(256) void k_gemm(const uint* __restrict__ X16, const uint* __restrict__ Wtaug,
    uint* __restrict__ feat16, float* __restrict__ el, float* __restrict__ er,
    uint* __restrict__ gmax_u){
  __shared__ uint sX[128*64];
  __shared__ uint sW[144*64];
  __shared__ float sgm[4][4];
  int t = threadIdx.x;
  int row0 = blockIdx.x*128;
  #pragma unroll
  for (int i=0;i<8;i++){
    int idx = t + 256*i;
    int r = idx>>4, cb = idx&15;
    int gr = row0 + r;
    uint4 v = make_uint4(0u,0u,0u,0u);
    if (gr < NN) v = *(const uint4*)&X16[(size_t)gr*64 + cb*4];
    *(uint4*)&sX[r*64 + ((cb*4) ^ ((r&7)<<2))] = v;
  }
  #pragma unroll
  for (int i=0;i<9;i++){
    int idx = t + 256*i;            // 0..2303 -> 144 rows
    int r = idx>>4, cb = idx&15;
    uint4 v = *(const uint4*)&Wtaug[(size_t)r*64 + cb*4];
    *(uint4*)&sW[r*64 + ((cb*4) ^ ((r&7)<<2))] = v;
  }
  __syncthreads();
  int w = t>>6, l = t&63;
  int lr = l&15, lk = l>>4;
  f32x4 acc[2][8];
  f32x4 acc_e[2];
  #pragma unroll
  for (int rf=0;rf<2;rf++){
    acc_e[rf] = (f32x4){0.f,0.f,0.f,0.f};
    #pragma unroll
    for (int cf=0;cf<8;cf++) acc[rf][cf] = (f32x4){0.f,0.f,0.f,0.f};
  }
  #pragma unroll
  for (int ks=0; ks<4; ks++){
    int cb = ks*4 + lk;
    bf16x8 a[2], b[8], baug;
    #pragma unroll
    for (int rf=0;rf<2;rf++){
      int r = w*32 + rf*16 + lr;
      a[rf] = *(const bf16x8*)&sX[r*64 + ((cb*4) ^ ((r&7)<<2))];
    }
    #pragma unroll
    for (int cf=0;cf<8;cf++){
      int r = cf*16 + lr;
      b[cf] = *(const bf16x8*)&sW[r*64 + ((cb*4) ^ ((r&7)<<2))];
    }
    {
      int r = 128 + lr;
      baug = *(const bf16x8*)&sW[r*64 + ((cb*4) ^ ((r&7)<<2))];
    }
    #pragma unroll
    for (int rf=0;rf<2;rf++){
      #pragma unroll
      for (int cf=0;cf<8;cf++)
        acc[rf][cf] = __builtin_amdgcn_mfma_f32_16x16x32_bf16(a[rf], b[cf], acc[rf][cf], 0,0,0);
      acc_e[rf] = __builtin_amdgcn_mfma_f32_16x16x32_bf16(a[rf], baug, acc_e[rf], 0,0,0);
    }
  }
  ushort* f16s = (ushort*)feat16;
  float gm = -3e38f;
  #pragma unroll
  for (int rf=0;rf<2;rf++){
    #pragma unroll
    for (int reg=0;reg<4;reg++){
      int grow = row0 + w*32 + rf*16 + lk*4 + reg;
      if (grow < NN){
        #pragma unroll
        for (int cf=0;cf<8;cf++)
          f16s[(size_t)grow*128 + cf*16 + lr] = f2bf(acc[rf][cf][reg]);
        float v = acc_e[rf][reg];
        if (lr<4){ el[grow*4 + lr] = v; gm = fmaxf(gm, v); }
        else if (lr<8){ er[grow*4 + lr-4] = v; }
      }
    }
  }
  gm = fmaxf(gm, __shfl_xor(gm,16));
  gm = fmaxf(gm, __shfl_xor(gm,32));
  if (l<4) sgm[w][l] = gm;
  __syncthreads();
  if (t<4){
    float m = fmaxf(fmaxf(sgm[0][t],sgm[1][t]), fmaxf(sgm[2][t],sgm[3][t]));
    atomicMax(&gmax_u[t], encf(m));
  }
}

// ---------- softmax exps + denominators (node-major): epack[h][e] = src|fp16(exp), s4[v][h] ----------
__global__ void k_soft(const int* __restrict__ offs, const uint* __restrict__ wpack,
                       const float4* __restrict__ el4, const float4* __restrict__ er4,
                       const uint* __restrict__ gmax_u,
                       uint* __restrict__ epack, float* __restrict__ s4){
  int node = (blockIdx.x*256 + threadIdx.x)>>6;
  int lane = threadIdx.x & 63;
  if (node>=NN) return;
  int eidx = lane>>2, hp = lane&3;
  int beg=offs[node], end=offs[node+1];
  float4 erv = er4[node];
  uint4 g = *(const uint4*)gmax_u;
  float4 m4 = make_float4(lrelu(decf(g.x)+erv.x), lrelu(decf(g.y)+erv.y),
                          lrelu(decf(g.z)+erv.z), lrelu(decf(g.w)+erv.w));
  float mh  = sel4(hp, m4);
  float erh = sel4(hp, erv);
  float s_acc = 0.f;
  for (int cb=beg; cb<end; cb+=16){
    int n = end-cb; if (n>16) n=16;
    int j = cb + (eidx<n ? eidx : n-1);
    uint src = wpack[j] & 0xffffu;
    float e = __expf(lrelu(sel4(hp, el4[src])+erh) - mh);
    if (eidx<n){
      s_acc += e;
      epack[hp*NE + j] = src | (f2h(e)<<16);
    }
  }
  s_acc += __shfl_xor(s_acc,4);
  s_acc += __shfl_xor(s_acc,8);
  s_acc += __shfl_xor(s_acc,16);
  s_acc += __shfl_xor(s_acc,32);
  if (lane<4) s4[node*4 + lane] = s_acc;
}

// ---------- GAT aggregation, column-sliced (pre-computed fp16 alphas) ----------
// FINAL=0: out16 = bf16(relu(rst+b+resid));  FINAL=1: outF = rst+b
template<int FINAL>
__global__ void k_gat_slice(const uint* __restrict__ feat16, const uint* __restrict__ epack,
                            const float* __restrict__ s4, const float* __restrict__ bias,
                            const int* __restrict__ offs, const float* __restrict__ resid,
                            float* __restrict__ outF, uint* __restrict__ out16){
  int slice = blockIdx.x & 7;
  int node = ((blockIdx.x>>3)<<2) + (threadIdx.x>>6);
  int lane = threadIdx.x & 63;
  if (node>=NN) return;
  int eg = lane>>3, cp = lane&7;
  int head = slice>>1;
  const uint* ep = epack + (size_t)head*NE;
  int beg=offs[node], end=offs[node+1];
  uint co = (uint)slice*32 + cp*4;
  const char* fbb = (const char*)feat16;
  float a0=0.f, a1=0.f;
  for (int cb=beg; cb<end; cb+=8){
    int j = cb + eg;
    uint pk = ep[j<end ? j : end-1];
    float e = (j<end)? h2f(pk>>16) : 0.f;
    uint u = *(const uint*)(fbb + ((pk & 0xffffu)*256u + co));
    a0 = fmaf(bflo(u), e, a0);
    a1 = fmaf(bfhi(u), e, a1);
  }
  a0 += __shfl_xor(a0,8);  a1 += __shfl_xor(a1,8);
  a0 += __shfl_xor(a0,16); a1 += __shfl_xor(a1,16);
  a0 += __shfl_xor(a0,32); a1 += __shfl_xor(a1,32);
  if (eg==0){
    float inv = (end>beg)? 1.f/s4[node*4 + head] : 0.f;
    int col = slice*16 + cp*2;
    float r0 = a0*inv + bias[col];
    float r1 = a1*inv + bias[col+1];
    if (FINAL==0){
      float2 rs = *(const float2*)&resid[(size_t)node*D + col];
      r0 = fmaxf(r0+rs.x, 0.f);
      r1 = fmaxf(r1+rs.y, 0.f);
      out16[(size_t)node*64 + slice*8 + cp] = pack2bf(r0,r1);
    } else {
      *(float2*)&outF[(size_t)node*D + col] = make_float2(r0,r1);
    }
  }
}

extern "C" void kernel_launch(void* const* d_in, const int* in_sizes, int n_in,
                              void* d_out, int out_size, void* d_ws, size_t ws_size,
                              hipStream_t stream){
  const float* in_feat = (const float*)d_in[0];
  const float* ew  = (const float*)d_in[1];
  const float* W0  = (const float*)d_in[2];
  const float* al0 = (const float*)d_in[3];
  const float* ar0 = (const float*)d_in[4];
  const float* b0  = (const float*)d_in[5];
  const float* W1  = (const float*)d_in[6];
  const float* al1 = (const float*)d_in[7];
  const float* ar1 = (const float*)d_in[8];
  const float* b1  = (const float*)d_in[9];
  const int* src = (const int*)d_in[10];
  const int* dst = (const int*)d_in[11];
  float* out = (float*)d_out;

  char* p = (char*)d_ws;
  auto alloc = [&](size_t b)->void*{ void* r=(void*)p; p += ((b+255)&~(size_t)255); return r; };
  int*   offs   = (int*)alloc((size_t)(NN+1)*4);
  int*   bcnt   = (int*)alloc((size_t)NB*4);
  int*   boff   = (int*)alloc((size_t)(NB+1)*4);
  int*   bcur   = (int*)alloc((size_t)NB*4);
  uint2* stg    = (uint2*)alloc((size_t)NE*8);
  uint*  wpack  = (uint*)alloc((size_t)NE*4);       // src | fp16(w)<<16, dst-sorted
  uint*  epack  = (uint*)alloc((size_t)NE*4*NH);    // [h][e]: src | fp16(exp)<<16
  float* s4     = (float*)alloc((size_t)NN*NH*4);   // softmax denominators
  uint*  h16    = (uint*)alloc((size_t)NN*64*4);    // layer input bf16 (sliced writes)
  uint*  x16    = (uint*)alloc((size_t)NN*64*4);    // post-wagg bf16 (GEMM input)
  uint*  feat16 = (uint*)alloc((size_t)NN*64*4);    // bf16 feat for gather
  uint*  Wt0    = (uint*)alloc((size_t)144*64*4);   // augmented W
  uint*  Wt1    = (uint*)alloc((size_t)144*64*4);
  float* el     = (float*)alloc((size_t)NN*NH*4);
  float* er     = (float*)alloc((size_t)NN*NH*4);
  uint*  gmax0  = (uint*)alloc(16);
  uint*  gmax1  = (uint*)alloc(16);

  hipMemsetAsync(bcnt, 0, (size_t)NB*4, stream);
  hipMemsetAsync(gmax0, 0, 16, stream);
  hipMemsetAsync(gmax1, 0, 16, stream);
  hipMemsetAsync(Wt0, 0, (size_t)144*64*4, stream);
  hipMemsetAsync(Wt1, 0, (size_t)144*64*4, stream);
  int nsb = (NE + 4095)/4096;  // 196
  k_bhist<<<nsb,256,0,stream>>>(dst, bcnt);
  k_bscan<<<1,512,0,stream>>>(bcnt, boff, bcur);
  k_binscat<<<nsb,256,0,stream>>>(src, dst, ew, bcur, stg);
  k_bfinal<<<NB,256,0,stream>>>(stg, boff, offs, wpack);
  int ncv = 8*((NN*8 + 255)/256);
  k_cvt_slice<<<ncv,256,0,stream>>>(in_feat, h16);
  k_cvtW<<<(128*64+255)/256,256,0,stream>>>(W0, Wt0);
  k_cvtW<<<(128*64+255)/256,256,0,stream>>>(W1, Wt1);
  k_prep<<<4,512,0,stream>>>(W0, al0, ar0, W1, al1, ar1, Wt0, Wt1);

  int nslc = 8*((NN+3)/4);     // sliced gather grids: 100000 blocks (slice = bid&7)
  int nwb  = (NN*64 + 255)/256; // 12500 node-major blocks
  int ngb  = (NN+127)/128;      // 391 GEMM blocks

  // layer 0
  k_wagg_slice<<<nslc,256,0,stream>>>(in_feat, h16, offs, wpack, x16);
  k_gemm<<<ngb,256,0,stream>>>(x16, Wt0, feat16, el, er, gmax0);
  k_soft<<<nwb,256,0,stream>>>(offs, wpack, (const float4*)el, (const float4*)er, gmax0, epack, s4);
  k_gat_slice<0><<<nslc,256,0,stream>>>(feat16, epack, s4, b0, offs, in_feat, nullptr, h16);
  // layer 1
  k_wagg_slice<<<nslc,256,0,stream>>>(nullptr, h16, offs, wpack, x16);
  k_gemm<<<ngb,256,0,stream>>>(x16, Wt1, feat16, el, er, gmax1);
  k_soft<<<nwb,256,0,stream>>>(offs, wpack, (const float4*)el, (const float4*)er, gmax1, epack, s4);
  k_gat_slice<1><<<nslc,256,0,stream>>>(feat16, epack, s4, b1, offs, nullptr, out, nullptr);
}

// Round 11
// 235.464 us; speedup vs baseline: 3.1135x; 3.1135x over previous
//
#include <hip/hip_runtime.h>
#include <hip/hip_fp16.h>

#define NN 50000
#define NE 800000
#define D 128
#define NH 4
#define NB 391   // (NN+127)/128 buckets of 128 nodes

typedef __attribute__((ext_vector_type(8))) short bf16x8;
typedef __attribute__((ext_vector_type(4))) float f32x4;

__device__ __forceinline__ float lrelu(float x){ return x > 0.f ? x : 0.2f*x; }
__device__ __forceinline__ float sel4(int h, float4 v){
  float r = v.x;
  r = (h==1)? v.y : r;
  r = (h==2)? v.z : r;
  r = (h==3)? v.w : r;
  return r;
}
__device__ __forceinline__ ushort f2bf(float f){
  union{ float f; uint i;} v; v.f=f;
  uint r = v.i + 0x7FFFu + ((v.i>>16)&1u);
  return (ushort)(r>>16);
}
__device__ __forceinline__ uint pack2bf(float x, float y){
  return (uint)f2bf(x) | ((uint)f2bf(y)<<16);
}
__device__ __forceinline__ float bflo(uint u){ return __uint_as_float(u<<16); }
__device__ __forceinline__ float bfhi(uint u){ return __uint_as_float(u & 0xffff0000u); }
__device__ __forceinline__ uint encf(float f){
  uint b = __float_as_uint(f);
  return (b & 0x80000000u) ? ~b : (b | 0x80000000u);
}
__device__ __forceinline__ float decf(uint e){
  return (e & 0x80000000u) ? __uint_as_float(e ^ 0x80000000u) : __uint_as_float(~e);
}
__device__ __forceinline__ uint f2h(float f){ return (uint)__half_as_ushort(__float2half(f)); }
__device__ __forceinline__ float h2f(uint u){ return __half2float(__ushort_as_half((ushort)u)); }

// ---------- CSR build: bucket histogram -> scan -> binned scatter -> bucket finalize ----------

__global__ void k_bhist(const int* __restrict__ dst, int* __restrict__ bcnt){
  __shared__ int c[NB];
  int t = threadIdx.x;
  for (int i=t;i<NB;i+=256) c[i]=0;
  __syncthreads();
  int base = blockIdx.x*4096;
  #pragma unroll
  for (int k=0;k<16;k++){
    int i = base + k*256 + t;
    if (i<NE) atomicAdd(&c[dst[i]>>7], 1);
  }
  __syncthreads();
  for (int i=t;i<NB;i+=256){ int v=c[i]; if (v) atomicAdd(&bcnt[i], v); }
}

__global__ void k_bscan(const int* __restrict__ bcnt, int* __restrict__ boff, int* __restrict__ bcur){
  __shared__ int sd[512];
  int t = threadIdx.x;
  int own = (t<NB)? bcnt[t] : 0;
  sd[t] = own;
  __syncthreads();
  for (int off=1; off<512; off<<=1){
    int v = (t>=off)? sd[t-off] : 0;
    __syncthreads();
    sd[t] += v;
    __syncthreads();
  }
  if (t<NB){
    int excl = sd[t]-own;
    boff[t]=excl; bcur[t]=excl;
  }
  if (t==0) boff[NB]=NE;
}

__global__ void k_binscat(const int* __restrict__ src, const int* __restrict__ dst,
                          const float* __restrict__ w, int* __restrict__ bcur,
                          uint2* __restrict__ stg){
  __shared__ int cnt[NB];
  __shared__ int st[NB];
  int t = threadIdx.x;
  for (int i=t;i<NB;i+=256) cnt[i]=0;
  __syncthreads();
  int base = blockIdx.x*4096;
  #pragma unroll
  for (int k=0;k<16;k++){
    int i = base + k*256 + t;
    if (i<NE) atomicAdd(&cnt[dst[i]>>7], 1);
  }
  __syncthreads();
  for (int i=t;i<NB;i+=256){
    int c = cnt[i];
    st[i] = c ? atomicAdd(&bcur[i], c) : 0;
    cnt[i] = 0;
  }
  __syncthreads();
  #pragma unroll
  for (int k=0;k<16;k++){
    int i = base + k*256 + t;
    if (i<NE){
      int d = dst[i];
      int b = d>>7;
      int pos = st[b] + atomicAdd(&cnt[b], 1);
      stg[pos] = make_uint2((uint)src[i] | ((uint)d<<16), __float_as_uint(w[i]));
    }
  }
}

// one block per bucket: exact CSR positions; writes offs + wpack (src | fp16(w)<<16)
__global__ void k_bfinal(const uint2* __restrict__ stg, const int* __restrict__ boff,
                         int* __restrict__ offs, uint* __restrict__ wpack){
  int b = blockIdx.x, t = threadIdx.x;
  int beg = boff[b], end = boff[b+1];
  int node0 = b<<7;
  int nnode = NN - node0; if (nnode>128) nnode=128;
  __shared__ int cnt[128];
  __shared__ int cur[128];
  if (t<128) cnt[t]=0;
  __syncthreads();
  for (int j=beg+t; j<end; j+=256)
    atomicAdd(&cnt[(stg[j].x>>16)&127], 1);
  __syncthreads();
  int own = (t<128)? cnt[t] : 0;
  for (int off=1; off<128; off<<=1){
    int v = (t<128 && t>=off)? cnt[t-off] : 0;
    __syncthreads();
    if (t<128) cnt[t] += v;
    __syncthreads();
  }
  if (t<128){
    int excl = cnt[t]-own;
    cur[t] = beg + excl;
    if (t<nnode) offs[node0+t] = beg + excl;
  }
  if (b==NB-1 && t==0) offs[NN]=NE;
  __syncthreads();
  for (int j=beg+t; j<end; j+=256){
    uint2 v = stg[j];
    int pos = atomicAdd(&cur[(v.x>>16)&127], 1);
    wpack[pos] = (v.x & 0xffffu) | (f2h(__uint_as_float(v.y))<<16);
  }
}

// ---------- conversions / prep ----------

__global__ void k_cvt(const float* __restrict__ in, uint* __restrict__ out16, int n2){
  int i = blockIdx.x*256 + threadIdx.x;
  if (i < n2){
    float2 f = *(const float2*)&in[(size_t)i*2];
    out16[i] = pack2bf(f.x, f.y);
  }
}

// W f32 [k=128][n=128] -> Wtaug rows 0..127: bf16 packed [n][k/2 uints]
__global__ void k_cvtW(const float* __restrict__ W, uint* __restrict__ Wt){
  int i = blockIdx.x*256 + threadIdx.x;
  if (i < 128*64){
    int n = i>>6, k2 = i&63;
    float a = W[(size_t)(2*k2)*128 + n];
    float b = W[(size_t)(2*k2+1)*128 + n];
    Wt[i] = pack2bf(a,b);
  }
}

// rows 128..135 of Wtaug: Wal[k][h] = sum_i W[k][h*32+i]*a[h*32+i]
__global__ void k_prep(const float* __restrict__ W0, const float* __restrict__ al0,
                       const float* __restrict__ ar0, const float* __restrict__ W1,
                       const float* __restrict__ al1, const float* __restrict__ ar1,
                       uint* __restrict__ aug0, uint* __restrict__ aug1){
  __shared__ float sv[128][4];
  int b = blockIdx.x, t = threadIdx.x;   // 512 threads
  const float* W = (b<2)? W0 : W1;
  const float* a = (b==0)? al0 : (b==1)? ar0 : (b==2)? al1 : ar1;
  uint* o = (b<2)? aug0 : aug1;
  int rbase = (b&1)? 132 : 128;
  int d = t>>2, h = t&3;
  float s = 0.f;
  #pragma unroll
  for (int i=0;i<32;i++) s += W[d*128 + h*32 + i] * a[h*32 + i];
  sv[d][h] = s;
  __syncthreads();
  if (t<256){
    int h2 = t>>6, k2 = t&63;
    o[(rbase+h2)*64 + k2] = pack2bf(sv[2*k2][h2], sv[2*k2+1][h2]);
  }
}

// ---------- weighted aggregation: x[v] = h[v] + sum w_e h[src_e]  (bf16 gather, 4B metadata) ----------
__global__ void k_wagg(const float* __restrict__ hinF, const uint* __restrict__ hin16,
                       const int* __restrict__ offs, const uint* __restrict__ wpack,
                       uint* __restrict__ xout16){
  int node = (blockIdx.x*256 + threadIdx.x)>>6;
  int lane = threadIdx.x & 63;
  if (node>=NN) return;
  int beg=offs[node], end=offs[node+1];
  int half = lane>>5, li = lane&31;
  const char* hb = (const char*)hin16;
  uint li8 = li*8;
  float a0=0.f,a1=0.f,a2=0.f,a3=0.f;
  if (half==0){
    if (hinF){
      float4 s4 = *(const float4*)&hinF[(size_t)node*D + li*4];
      a0=s4.x; a1=s4.y; a2=s4.z; a3=s4.w;
    } else {
      uint2 su = *(const uint2*)&hin16[(size_t)node*64 + li*2];
      a0=bflo(su.x); a1=bfhi(su.x); a2=bflo(su.y); a3=bfhi(su.y);
    }
  }
  for (int cb=beg; cb<end; cb+=64){
    int n = end-cb; if (n>64) n=64;
    int idx = cb + (lane<n ? lane : n-1);
    uint ed = wpack[idx];
    uint spo = (ed & 0xffffu)<<8;
    float wp = h2f(ed>>16);
    int iters = (n+1)>>1;
    for (int i0=0; i0<iters; i0+=8){
      uint2 u[8]; float wk[8];
      #pragma unroll
      for (int k=0;k<8;k++){
        int q = 2*(i0+k) + half;
        uint so = __shfl(spo, q & 63);
        float wq = __shfl(wp, q & 63);
        wk[k] = (q<n)? wq : 0.f;
        u[k] = *(const uint2*)(hb + (so + li8));
      }
      #pragma unroll
      for (int k=0;k<8;k++){
        a0 = fmaf(bflo(u[k].x), wk[k], a0);
        a1 = fmaf(bfhi(u[k].x), wk[k], a1);
        a2 = fmaf(bflo(u[k].y), wk[k], a2);
        a3 = fmaf(bfhi(u[k].y), wk[k], a3);
      }
    }
  }
  a0 += __shfl_xor(a0,32); a1 += __shfl_xor(a1,32);
  a2 += __shfl_xor(a2,32); a3 += __shfl_xor(a3,32);
  if (half==0){
    uint2 o; o.x = pack2bf(a0,a1); o.y = pack2bf(a2,a3);
    *(uint2*)&xout16[(size_t)node*64 + li*2] = o;
  }
}

// ---------- MFMA GEMM (bf16 in, f32 acc), aug columns give el/er; shuffle-free epilogue ----------
__global__ __launch_bounds__(256) void k_gemm(const uint* __restrict__ X16, const uint* __restrict__ Wtaug,
    uint* __restrict__ feat16, float* __restrict__ el, float* __restrict__ er,
    uint* __restrict__ gmax_u){
  __shared__ uint sX[128*64];
  __shared__ uint sW[144*64];
  __shared__ float sgm[4][4];
  int t = threadIdx.x;
  int row0 = blockIdx.x*128;
  #pragma unroll
  for (int i=0;i<8;i++){
    int idx = t + 256*i;
    int r = idx>>4, cb = idx&15;
    int gr = row0 + r;
    uint4 v = make_uint4(0u,0u,0u,0u);
    if (gr < NN) v = *(const uint4*)&X16[(size_t)gr*64 + cb*4];
    *(uint4*)&sX[r*64 + ((cb*4) ^ ((r&7)<<2))] = v;
  }
  #pragma unroll
  for (int i=0;i<9;i++){
    int idx = t + 256*i;            // 0..2303 -> 144 rows
    int r = idx>>4, cb = idx&15;
    uint4 v = *(const uint4*)&Wtaug[(size_t)r*64 + cb*4];
    *(uint4*)&sW[r*64 + ((cb*4) ^ ((r&7)<<2))] = v;
  }
  __syncthreads();
  int w = t>>6, l = t&63;
  int lr = l&15, lk = l>>4;
  f32x4 acc[2][8];
  f32x4 acc_e[2];
  #pragma unroll
  for (int rf=0;rf<2;rf++){
    acc_e[rf] = (f32x4){0.f,0.f,0.f,0.f};
    #pragma unroll
    for (int cf=0;cf<8;cf++) acc[rf][cf] = (f32x4){0.f,0.f,0.f,0.f};
  }
  #pragma unroll
  for (int ks=0; ks<4; ks++){
    int cb = ks*4 + lk;
    bf16x8 a[2], b[8], baug;
    #pragma unroll
    for (int rf=0;rf<2;rf++){
      int r = w*32 + rf*16 + lr;
      a[rf] = *(const bf16x8*)&sX[r*64 + ((cb*4) ^ ((r&7)<<2))];
    }
    #pragma unroll
    for (int cf=0;cf<8;cf++){
      int r = cf*16 + lr;
      b[cf] = *(const bf16x8*)&sW[r*64 + ((cb*4) ^ ((r&7)<<2))];
    }
    {
      int r = 128 + lr;
      baug = *(const bf16x8*)&sW[r*64 + ((cb*4) ^ ((r&7)<<2))];
    }
    #pragma unroll
    for (int rf=0;rf<2;rf++){
      #pragma unroll
      for (int cf=0;cf<8;cf++)
        acc[rf][cf] = __builtin_amdgcn_mfma_f32_16x16x32_bf16(a[rf], b[cf], acc[rf][cf], 0,0,0);
      acc_e[rf] = __builtin_amdgcn_mfma_f32_16x16x32_bf16(a[rf], baug, acc_e[rf], 0,0,0);
    }
  }
  ushort* f16s = (ushort*)feat16;
  float gm = -3e38f;
  #pragma unroll
  for (int rf=0;rf<2;rf++){
    #pragma unroll
    for (int reg=0;reg<4;reg++){
      int grow = row0 + w*32 + rf*16 + lk*4 + reg;
      if (grow < NN){
        #pragma unroll
        for (int cf=0;cf<8;cf++)
          f16s[(size_t)grow*128 + cf*16 + lr] = f2bf(acc[rf][cf][reg]);
        float v = acc_e[rf][reg];
        if (lr<4){ el[grow*4 + lr] = v; gm = fmaxf(gm, v); }
        else if (lr<8){ er[grow*4 + lr-4] = v; }
      }
    }
  }
  gm = fmaxf(gm, __shfl_xor(gm,16));
  gm = fmaxf(gm, __shfl_xor(gm,32));
  if (l<4) sgm[w][l] = gm;
  __syncthreads();
  if (t<4){
    float m = fmaxf(fmaxf(sgm[0][t],sgm[1][t]), fmaxf(sgm[2][t],sgm[3][t]));
    atomicMax(&gmax_u[t], encf(m));
  }
}

// ---------- GAT edge-softmax + aggregation (pipelined metadata prefetch) ----------
// FINAL=0: out16 = bf16(relu(rst+b+resid));  FINAL=1: outF = rst+b
template<int FINAL>
__global__ void k_gat(const uint* __restrict__ feat16, const float4* __restrict__ el4,
                      const float4* __restrict__ er4, const uint* __restrict__ gmax_u,
                      const float* __restrict__ bias, const int* __restrict__ offs,
                      const uint* __restrict__ wpack, const float* __restrict__ resid,
                      float* __restrict__ outF, uint* __restrict__ out16){
  int node = (blockIdx.x*256 + threadIdx.x)>>6;
  int lane = threadIdx.x & 63;
  if (node>=NN) return;
  int beg=offs[node], end=offs[node+1];
  int half = lane>>5, li = lane&31;
  int hF = li>>3;           // head of this lane's 4 columns
  int hp = lane & 3;        // head this lane's exp covers
  int eidx = lane>>2;
  const char* fb = (const char*)feat16;
  uint li8 = li*8;
  float4 erv = er4[node];
  uint4 g = *(const uint4*)gmax_u;
  float4 m4 = make_float4(lrelu(decf(g.x)+erv.x), lrelu(decf(g.y)+erv.y),
                          lrelu(decf(g.z)+erv.z), lrelu(decf(g.w)+erv.w));
  float mh  = sel4(hp, m4);
  float erh = sel4(hp, erv);
  float s_acc = 0.f;
  float a0=0.f,a1=0.f,a2=0.f,a3=0.f;
  if (beg < end){
    int cb = beg;
    int n = end-beg; if (n>16) n=16;
    uint ed = wpack[beg + (eidx<n ? eidx : n-1)];
    float4 ev = el4[ed & 0xffffu];
    while (1){
      uint spo = (ed & 0xffffu)<<8;
      float e = __expf(lrelu(sel4(hp,ev)+erh) - mh);
      e = (eidx<n) ? e : 0.f;
      s_acc += e;
      // issue current chunk's 8 row-loads (16 rows across halves)
      uint2 u[8]; float eh[8];
      #pragma unroll
      for (int k=0;k<8;k++){
        int bidx = (2*k + half)<<2;
        uint so = __shfl(spo, bidx);
        eh[k] = __shfl(e, bidx + hF);
        u[k] = *(const uint2*)(fb + (so + li8));
      }
      // prefetch next chunk's metadata while row-loads are in flight
      int cb2 = cb + 16;
      int n2 = 0; uint ed2 = 0u;
      float4 ev2 = make_float4(0.f,0.f,0.f,0.f);
      if (cb2 < end){
        n2 = end-cb2; if (n2>16) n2=16;
        ed2 = wpack[cb2 + (eidx<n2 ? eidx : n2-1)];
        ev2 = el4[ed2 & 0xffffu];
      }
      // consume current chunk
      #pragma unroll
      for (int k=0;k<8;k++){
        a0 = fmaf(bflo(u[k].x), eh[k], a0);
        a1 = fmaf(bfhi(u[k].x), eh[k], a1);
        a2 = fmaf(bflo(u[k].y), eh[k], a2);
        a3 = fmaf(bfhi(u[k].y), eh[k], a3);
      }
      if (cb2 >= end) break;
      cb = cb2; n = n2; ed = ed2; ev = ev2;
    }
  }
  s_acc += __shfl_xor(s_acc,4);
  s_acc += __shfl_xor(s_acc,8);
  s_acc += __shfl_xor(s_acc,16);
  s_acc += __shfl_xor(s_acc,32);
  float sh = __shfl(s_acc, hF);
  a0 += __shfl_xor(a0,32); a1 += __shfl_xor(a1,32);
  a2 += __shfl_xor(a2,32); a3 += __shfl_xor(a3,32);
  if (half==0){
    float inv = (end>beg)? 1.f/sh : 0.f;
    float4 bv = *(const float4*)&bias[li*4];
    float r0 = a0*inv + bv.x;
    float r1 = a1*inv + bv.y;
    float r2 = a2*inv + bv.z;
    float r3 = a3*inv + bv.w;
    if (FINAL==0){
      float4 rs = *(const float4*)&resid[(size_t)node*D + li*4];
      r0 = fmaxf(r0+rs.x, 0.f);
      r1 = fmaxf(r1+rs.y, 0.f);
      r2 = fmaxf(r2+rs.z, 0.f);
      r3 = fmaxf(r3+rs.w, 0.f);
      uint2 o16; o16.x = pack2bf(r0,r1); o16.y = pack2bf(r2,r3);
      *(uint2*)&out16[(size_t)node*64 + li*2] = o16;
    } else {
      *(float4*)&outF[(size_t)node*D + li*4] = make_float4(r0,r1,r2,r3);
    }
  }
}

extern "C" void kernel_launch(void* const* d_in, const int* in_sizes, int n_in,
                              void* d_out, int out_size, void* d_ws, size_t ws_size,
                              hipStream_t stream){
  const float* in_feat = (const float*)d_in[0];
  const float* ew  = (const float*)d_in[1];
  const float* W0  = (const float*)d_in[2];
  const float* al0 = (const float*)d_in[3];
  const float* ar0 = (const float*)d_in[4];
  const float* b0  = (const float*)d_in[5];
  const float* W1  = (const float*)d_in[6];
  const float* al1 = (const float*)d_in[7];
  const float* ar1 = (const float*)d_in[8];
  const float* b1  = (const float*)d_in[9];
  const int* src = (const int*)d_in[10];
  const int* dst = (const int*)d_in[11];
  float* out = (float*)d_out;

  char* p = (char*)d_ws;
  auto alloc = [&](size_t b)->void*{ void* r=(void*)p; p += ((b+255)&~(size_t)255); return r; };
  int*   offs   = (int*)alloc((size_t)(NN+1)*4);
  int*   bcnt   = (int*)alloc((size_t)NB*4);
  int*   boff   = (int*)alloc((size_t)(NB+1)*4);
  int*   bcur   = (int*)alloc((size_t)NB*4);
  uint2* stg    = (uint2*)alloc((size_t)NE*8);
  uint*  wpack  = (uint*)alloc((size_t)NE*4);      // src | fp16(w)<<16, dst-sorted
  uint*  h16    = (uint*)alloc((size_t)NN*64*4);   // layer input bf16; overwritten by k_gat<0>
  uint*  x16    = (uint*)alloc((size_t)NN*64*4);   // post-wagg bf16 (GEMM input)
  uint*  feat16 = (uint*)alloc((size_t)NN*64*4);   // bf16 feat for gather
  uint*  Wt0    = (uint*)alloc((size_t)144*64*4);  // augmented: rows 0-127 W, 128-135 Wal/War, 136-143 zero
  uint*  Wt1    = (uint*)alloc((size_t)144*64*4);
  float* el     = (float*)alloc((size_t)NN*NH*4);
  float* er     = (float*)alloc((size_t)NN*NH*4);
  uint*  gmax0  = (uint*)alloc(16);
  uint*  gmax1  = (uint*)alloc(16);

  hipMemsetAsync(bcnt, 0, (size_t)NB*4, stream);
  hipMemsetAsync(gmax0, 0, 16, stream);
  hipMemsetAsync(gmax1, 0, 16, stream);
  hipMemsetAsync(Wt0, 0, (size_t)144*64*4, stream);
  hipMemsetAsync(Wt1, 0, (size_t)144*64*4, stream);
  int nsb = (NE + 4095)/4096;  // 196
  k_bhist<<<nsb,256,0,stream>>>(dst, bcnt);
  k_bscan<<<1,512,0,stream>>>(bcnt, boff, bcur);
  k_binscat<<<nsb,256,0,stream>>>(src, dst, ew, bcur, stg);
  k_bfinal<<<NB,256,0,stream>>>(stg, boff, offs, wpack);
  k_cvt<<<(NN*64+255)/256,256,0,stream>>>(in_feat, h16, NN*64);
  k_cvtW<<<(128*64+255)/256,256,0,stream>>>(W0, Wt0);
  k_cvtW<<<(128*64+255)/256,256,0,stream>>>(W1, Wt1);
  k_prep<<<4,512,0,stream>>>(W0, al0, ar0, W1, al1, ar1, Wt0, Wt1);

  int nwb = (NN*64 + 255)/256; // 12500 blocks (4 waves = 4 nodes each)
  int ngb = (NN+127)/128;      // 391 GEMM blocks

  // layer 0
  k_wagg<<<nwb,256,0,stream>>>(in_feat, h16, offs, wpack, x16);
  k_gemm<<<ngb,256,0,stream>>>(x16, Wt0, feat16, el, er, gmax0);
  k_gat<0><<<nwb,256,0,stream>>>(feat16, (const float4*)el, (const float4*)er, gmax0, b0,
                                 offs, wpack, in_feat, nullptr, h16);
  // layer 1
  k_wagg<<<nwb,256,0,stream>>>(nullptr, h16, offs, wpack, x16);
  k_gemm<<<ngb,256,0,stream>>>(x16, Wt1, feat16, el, er, gmax1);
  k_gat<1><<<nwb,256,0,stream>>>(feat16, (const float4*)el, (const float4*)er, gmax1, b1,
                                 offs, wpack, nullptr, out, nullptr);
}